// Round 8
// baseline (629.260 us; speedup 1.0000x reference)
//
#include <hip/hip_runtime.h>
#include <hip/hip_bf16.h>

#define DIM 128
#define N_SEG 100000
#define N_TOT (N_SEG + 1)  // offsets array length
#define NB 98              // ceil(N_TOT / 1024)

typedef __attribute__((ext_vector_type(8))) __bf16 bf16x8;
typedef __attribute__((ext_vector_type(4))) float f32x4;

// ---- d_ws layout (u32 element offsets) -------------------------------------
// [0] flag (idx width probe)   [1] ucnt (number of work units)
#define WS_OFF 64                    // off[N_TOT]: counts -> exclusive offsets
#define WS_RUN (WS_OFF + N_TOT + 1)  // run[N_SEG]: rank-scatter cursors
#define WS_BSUM (WS_RUN + N_SEG)     // bsum[128]
#define WS_BPRE (WS_BSUM + 128)      // bpre[128]
#define WS_UNITS (WS_BPRE + 128)     // uint2 units[300K] (600K u32, 8B aligned)
#define WS_ORDER (WS_UNITS + 600000) // order[1.6M]
// total ~= 2.4M u32 = 9.6 MB

// ---------------------------------------------------------------------------
// Probe: int64 index => every odd 32-bit word is 0. flag=1 => int32 layout.
// ---------------------------------------------------------------------------
__global__ void idx_probe_kernel(const unsigned* __restrict__ idx32,
                                 unsigned* __restrict__ flag, int n) {
  unsigned v = 0;
  const int stride = gridDim.x * blockDim.x;
  for (int i = blockIdx.x * blockDim.x + threadIdx.x; i < n; i += stride)
    v |= idx32[2 * i + 1];
  if (v) atomicOr(flag, 1u);
}

// vectorized histogram: uint4 = 2 int64 elems or 4 int32 elems
__global__ void hist_kernel(const uint4* __restrict__ idx4,
                            const unsigned* __restrict__ flag,
                            unsigned* __restrict__ cnt, int n) {
  const bool idx64 = (*flag == 0u);
  const int stride = gridDim.x * blockDim.x;
  const int t0 = blockIdx.x * blockDim.x + threadIdx.x;
  if (idx64) {
    const int nv = n >> 1;  // uint4 count
    for (int i = t0; i < nv; i += stride) {
      const uint4 v = idx4[i];
      atomicAdd(&cnt[v.x], 1u);
      atomicAdd(&cnt[v.z], 1u);
    }
  } else {
    const int nv = n >> 2;
    for (int i = t0; i < nv; i += stride) {
      const uint4 v = idx4[i];
      atomicAdd(&cnt[v.x], 1u);
      atomicAdd(&cnt[v.y], 1u);
      atomicAdd(&cnt[v.z], 1u);
      atomicAdd(&cnt[v.w], 1u);
    }
  }
}

// ---- coalesced exclusive scan over off[N_TOT], fused unit-build -------------
__global__ __launch_bounds__(1024) void scan_bsum(const unsigned* __restrict__ off,
                                                  unsigned* __restrict__ bsum) {
  __shared__ unsigned ws[16];
  const int t = threadIdx.x;
  const int i = blockIdx.x * 1024 + t;
  unsigned v = (i < N_TOT) ? off[i] : 0u;
#pragma unroll
  for (int d = 1; d < 64; d <<= 1) v += __shfl_xor(v, d);
  if ((t & 63) == 0) ws[t >> 6] = v;
  __syncthreads();
  if (t == 0) {
    unsigned s = 0;
#pragma unroll
    for (int w = 0; w < 16; ++w) s += ws[w];
    bsum[blockIdx.x] = s;
  }
}

__global__ __launch_bounds__(128) void scan_btop(unsigned* __restrict__ bsum,
                                                 unsigned* __restrict__ bpre) {
  __shared__ unsigned part[128];
  const int t = threadIdx.x;
  unsigned v = (t < NB) ? bsum[t] : 0u;
  part[t] = v;
  __syncthreads();
  for (int d = 1; d < 128; d <<= 1) {
    const unsigned u = (t >= d) ? part[t - d] : 0u;
    __syncthreads();
    part[t] += u;
    __syncthreads();
  }
  bpre[t] = part[t] - v;  // exclusive
}

// scan_fixup + unit_build fused: thread for segment s has base=excl, count=v
// locally -> emits the <=16-row units directly (wave-aggregated ucnt atomic:
// 1.6K single-address atomics instead of 100K), zeroes the rare out rows
// (empty / multi-unit) so no 51 MB out-memset is needed.
__global__ __launch_bounds__(1024) void scan_fixup_build(
    unsigned* __restrict__ off, unsigned* __restrict__ run,
    const unsigned* __restrict__ bpre, uint2* __restrict__ units,
    unsigned* __restrict__ ucnt, float* __restrict__ out) {
  __shared__ unsigned wsum[16], wpre[16];
  const int t = threadIdx.x;
  const int lane = t & 63;
  const int wv = t >> 6;
  const int i = blockIdx.x * 1024 + t;
  const unsigned v = (i < N_TOT) ? off[i] : 0u;
  unsigned s = v;
#pragma unroll
  for (int d = 1; d < 64; d <<= 1) {
    const unsigned u = __shfl_up(s, d);
    if (lane >= d) s += u;
  }
  if (lane == 63) wsum[wv] = s;
  __syncthreads();
  if (t < 16) {
    unsigned w = wsum[t];
    unsigned ps = w;
#pragma unroll
    for (int d = 1; d < 16; d <<= 1) {
      const unsigned u = __shfl_up(ps, d, 16);
      if (t >= d) ps += u;
    }
    wpre[t] = ps - w;  // exclusive across waves
  }
  __syncthreads();
  const unsigned excl = (s - v) + wpre[wv] + bpre[blockIdx.x];
  if (i < N_TOT) off[i] = excl;
  if (i < N_SEG) run[i] = excl;

  // ---- fused unit emission ------------------------------------------------
  const unsigned c = (i < N_SEG) ? v : 0u;
  const unsigned nu = (c + 15u) >> 4;
  if (i < N_SEG && (c == 0u || nu > 1u)) {  // rare rows: zero for atomic base
    f32x4* orow = (f32x4*)(out + (size_t)i * DIM);
#pragma unroll
    for (int k = 0; k < DIM / 4; ++k) orow[k] = (f32x4){0.f, 0.f, 0.f, 0.f};
  }
  // wave-aggregated allocation in units[]
  unsigned inc = nu;
#pragma unroll
  for (int d = 1; d < 64; d <<= 1) {
    const unsigned u = __shfl_up(inc, d);
    if (lane >= d) inc += u;
  }
  unsigned base = 0;
  if (lane == 63 && inc > 0) base = atomicAdd(ucnt, inc);
  base = __shfl(base, 63);
  unsigned pos = base + inc - nu;
  const unsigned solo = (nu == 1u) ? (1u << 23) : 0u;
  for (unsigned k = 0; k < nu; ++k) {
    const unsigned cnt = min(16u, c - 16u * k);
    uint2 ent;
    ent.x = excl + 16u * k;
    ent.y = (unsigned)i | ((cnt - 1u) << 17) | solo;
    units[pos + k] = ent;
  }
}

// vectorized rank-scatter: uint4 = 2 int64 elems or 4 int32 elems
__global__ void rank_kernel(const uint4* __restrict__ idx4,
                            const unsigned* __restrict__ flag,
                            unsigned* __restrict__ run,
                            unsigned* __restrict__ order, int n) {
  const bool idx64 = (*flag == 0u);
  const int stride = gridDim.x * blockDim.x;
  const int t0 = blockIdx.x * blockDim.x + threadIdx.x;
  if (idx64) {
    const int nv = n >> 1;
    for (int i = t0; i < nv; i += stride) {
      const uint4 v = idx4[i];
      unsigned p0 = atomicAdd(&run[v.x], 1u);
      order[p0] = 2u * i;
      unsigned p1 = atomicAdd(&run[v.z], 1u);
      order[p1] = 2u * i + 1u;
    }
  } else {
    const int nv = n >> 2;
    for (int i = t0; i < nv; i += stride) {
      const uint4 v = idx4[i];
      unsigned p0 = atomicAdd(&run[v.x], 1u);
      order[p0] = 4u * i;
      unsigned p1 = atomicAdd(&run[v.y], 1u);
      order[p1] = 4u * i + 1u;
      unsigned p2 = atomicAdd(&run[v.z], 1u);
      order[p2] = 4u * i + 2u;
      unsigned p3 = atomicAdd(&run[v.w], 1u);
      order[p3] = 4u * i + 3u;
    }
  }
}

// ---------------------------------------------------------------------------
// Main: one wave per 16-row unit, processed in PAIRS per iteration so two
// units' e-data (16 KB/wave) are in flight at every wait point (R7 at 1-deep
// measured ~3.5 TB/s; doubling in-flight bytes targets ~5 TB/s).
// Pipeline state entering iter for pair p: data(p) in regs, ids(p+1) ready,
// descs(p), (p+1), (p+2) held. Runs fat at (256,2) — (256,4)'s 128-reg cap
// spilled to GBs of scratch HBM traffic (R3/R6 evidence).
//
// Fragment layouts (mfma_f32_16x16x32_bf16, m89-verified):
//   A (lane l, elem j): e[row_{l&15}][32t + (l>>4)*8 + j]
//   B (lane l, elem j): W[k0*16 + (l&15)][32t + (l>>4)*8 + j]   (LDS frags)
//   C/D (lane l, reg r): h[tile row (l>>4)*4 + r][k0*16 + (l&15)]
// ---------------------------------------------------------------------------
__device__ __forceinline__ int cnt_of(uint2 d) {
  return (int)((d.y >> 17) & 15u) + 1;
}

__device__ __forceinline__ unsigned load_id(const unsigned* __restrict__ order,
                                            uint2 d, int lr) {
  const int c = cnt_of(d);
  return order[d.x + (lr < c ? lr : c - 1)];
}

__device__ __forceinline__ void load_row(f32x4* dst,
                                         const float* __restrict__ e,
                                         unsigned row, int lg) {
  const float* erow = e + (size_t)row * DIM + lg * 8;
#pragma unroll
  for (int t = 0; t < 4; ++t) {
    dst[2 * t] = *(const f32x4*)(erow + t * 32);
    dst[2 * t + 1] = *(const f32x4*)(erow + t * 32 + 4);
  }
}

__device__ __forceinline__ void cvt_frag(bf16x8* af, const f32x4* eb) {
#pragma unroll
  for (int t = 0; t < 4; ++t) {
    f32x4 a0 = eb[2 * t], a1 = eb[2 * t + 1];
    bf16x8 f;
    f[0] = (__bf16)a0[0]; f[1] = (__bf16)a0[1];
    f[2] = (__bf16)a0[2]; f[3] = (__bf16)a0[3];
    f[4] = (__bf16)a1[0]; f[5] = (__bf16)a1[1];
    f[6] = (__bf16)a1[2]; f[7] = (__bf16)a1[3];
    af[t] = f;
  }
}

__device__ __forceinline__ void compute_store(const bf16x8* af,
                                              const bf16x8* wlds,
                                              const float* bias, uint2 d,
                                              bool active, int lg, int lr,
                                              int lane,
                                              float* __restrict__ out) {
  const int seg = (int)(d.y & 0x1FFFFu);
  const int cnt = cnt_of(d);
  const bool solo = (d.y >> 23) & 1u;

  float colsum[8] = {0.f, 0.f, 0.f, 0.f, 0.f, 0.f, 0.f, 0.f};
#pragma unroll
  for (int half = 0; half < 2; ++half) {
    f32x4 acc[4];
#pragma unroll
    for (int k = 0; k < 4; ++k) acc[k] = (f32x4){0.f, 0.f, 0.f, 0.f};
#pragma unroll
    for (int t = 0; t < 4; ++t) {
#pragma unroll
      for (int k = 0; k < 4; ++k) {
        bf16x8 bf = wlds[((half * 4 + k) * 4 + t) * 64 + lane];
        acc[k] = __builtin_amdgcn_mfma_f32_16x16x32_bf16(af[t], bf, acc[k],
                                                         0, 0, 0);
      }
    }
#pragma unroll
    for (int r = 0; r < 4; ++r) {
      const bool valid = (lg * 4 + r) < cnt;
#pragma unroll
      for (int k = 0; k < 4; ++k) {
        const float v = fmaxf(acc[k][r] + bias[half * 4 + k], 0.f);
        colsum[half * 4 + k] += valid ? v : 0.f;
      }
    }
  }
#pragma unroll
  for (int k0 = 0; k0 < 8; ++k0) {
    float s = colsum[k0];
    s += __shfl_xor(s, 16);
    s += __shfl_xor(s, 32);
    colsum[k0] = s;
  }
  if (active && lg == 0) {
    float* orow = out + (size_t)seg * DIM + lr;
    if (solo) {
#pragma unroll
      for (int k0 = 0; k0 < 8; ++k0) orow[k0 * 16] = colsum[k0];
    } else {
#pragma unroll
      for (int k0 = 0; k0 < 8; ++k0)
        unsafeAtomicAdd(orow + k0 * 16, colsum[k0]);
    }
  }
}

__global__ __launch_bounds__(256, 2) void fused_main(
    const float* __restrict__ e, const float* __restrict__ W,
    const float* __restrict__ bias_p, const unsigned* __restrict__ order,
    const uint2* __restrict__ units, const unsigned* __restrict__ ucnt,
    float* __restrict__ out) {
  __shared__ bf16x8 wlds[2048];  // 32 KiB: [k0][t][lane] fragment-major

  const int tid = threadIdx.x;
  const int wave = tid >> 6;
  const int lane = tid & 63;
  const int lr = lane & 15;
  const int lg = lane >> 4;

  // one-time: stage W as bf16 fragments into LDS
#pragma unroll
  for (int j = 0; j < 8; ++j) {
    const int g = (tid << 3) | j;
    const int gl = g & 63;
    const int tt = (g >> 6) & 3;
    const int k0 = g >> 8;
    const int row = k0 * 16 + (gl & 15);
    const int col = tt * 32 + (gl >> 4) * 8;
    const float* src = W + (size_t)row * DIM + col;
    f32x4 w0 = *(const f32x4*)src;
    f32x4 w1 = *(const f32x4*)(src + 4);
    bf16x8 f;
    f[0] = (__bf16)w0[0]; f[1] = (__bf16)w0[1];
    f[2] = (__bf16)w0[2]; f[3] = (__bf16)w0[3];
    f[4] = (__bf16)w1[0]; f[5] = (__bf16)w1[1];
    f[6] = (__bf16)w1[2]; f[7] = (__bf16)w1[3];
    wlds[g] = f;
  }
  __syncthreads();

  float bias[8];
#pragma unroll
  for (int k0 = 0; k0 < 8; ++k0) bias[k0] = bias_p[k0 * 16 + lr];

  const int n_units = (int)*ucnt;
  const int wid = blockIdx.x * 4 + wave;
  const int nw = gridDim.x * 4;
  if (wid >= n_units) return;
  const int last = n_units - 1;

#define DESC_AT(u) units[(u) < n_units ? (u) : last]

  // ---- prologue: fill pipeline (pair0 data, pair1 ids, descs 0..2) --------
  uint2 da0 = DESC_AT(wid);
  uint2 da1 = DESC_AT(wid + nw);
  const unsigned ia0 = load_id(order, da0, lr);
  const unsigned ia1 = load_id(order, da1, lr);
  f32x4 e0[8], e1[8];
  load_row(e0, e, ia0, lg);
  load_row(e1, e, ia1, lg);
  uint2 db0 = DESC_AT(wid + 2 * nw);
  uint2 db1 = DESC_AT(wid + 3 * nw);
  unsigned i0 = load_id(order, db0, lr);
  unsigned i1 = load_id(order, db1, lr);
  uint2 dc0 = DESC_AT(wid + 4 * nw);
  uint2 dc1 = DESC_AT(wid + 5 * nw);

  for (int u = wid; u < n_units; u += 2 * nw) {
    // 1. consume pair p (waits on e0/e1 issued last iteration)
    bf16x8 af0[4], af1[4];
    cvt_frag(af0, e0);
    cvt_frag(af1, e1);
    // 2. issue data for pair p+1 (ids ready since last iteration)
    load_row(e0, e, i0, lg);
    load_row(e1, e, i1, lg);
    // 3. issue ids for pair p+2 (descs held)
    i0 = load_id(order, dc0, lr);
    i1 = load_id(order, dc1, lr);
    // 4. issue descs for pair p+3
    uint2 dn0 = DESC_AT(u + 6 * nw);
    uint2 dn1 = DESC_AT(u + 7 * nw);
    // 5. MFMA + reduce + store both units (LDS operands: lgkmcnt only)
    compute_store(af0, wlds, bias, da0, true, lg, lr, lane, out);
    compute_store(af1, wlds, bias, da1, (u + nw) < n_units, lg, lr, lane, out);
    // 6. rotate descriptor pipeline
    da0 = db0; da1 = db1;
    db0 = dc0; db1 = dc1;
    dc0 = dn0; dc1 = dn1;
  }
#undef DESC_AT
}

extern "C" void kernel_launch(void* const* d_in, const int* in_sizes, int n_in,
                              void* d_out, int out_size, void* d_ws, size_t ws_size,
                              hipStream_t stream) {
  const float* e = (const float*)d_in[0];
  const int* idx = (const int*)d_in[1];
  const float* W = (const float*)d_in[2];
  const float* b = (const float*)d_in[3];
  float* out = (float*)d_out;
  unsigned* ws32 = (unsigned*)d_ws;

  const int n_e = in_sizes[0] / DIM;  // 1,600,000 rows

  // zero flag + ucnt + off[] only (~400 KB); out rows handled in fixup_build
  hipMemsetAsync(d_ws, 0, (size_t)(WS_OFF + N_TOT) * sizeof(unsigned), stream);

  idx_probe_kernel<<<304, 256, 0, stream>>>((const unsigned*)idx, ws32,
                                            n_e / 2);
  hist_kernel<<<1024, 256, 0, stream>>>((const uint4*)idx, ws32, ws32 + WS_OFF,
                                        n_e);
  scan_bsum<<<NB, 1024, 0, stream>>>(ws32 + WS_OFF, ws32 + WS_BSUM);
  scan_btop<<<1, 128, 0, stream>>>(ws32 + WS_BSUM, ws32 + WS_BPRE);
  scan_fixup_build<<<NB, 1024, 0, stream>>>(
      ws32 + WS_OFF, ws32 + WS_RUN, ws32 + WS_BPRE,
      (uint2*)(ws32 + WS_UNITS), ws32 + 1, out);
  rank_kernel<<<1024, 256, 0, stream>>>((const uint4*)idx, ws32, ws32 + WS_RUN,
                                        ws32 + WS_ORDER, n_e);
  fused_main<<<512, 256, 0, stream>>>(e, W, b, ws32 + WS_ORDER,
                                      (const uint2*)(ws32 + WS_UNITS),
                                      ws32 + 1, out);
}

// Round 9
// 451.764 us; speedup vs baseline: 1.3929x; 1.3929x over previous
//
#include <hip/hip_runtime.h>
#include <hip/hip_bf16.h>

#define DIM 128
#define N_SEG 100000
#define N_TOT (N_SEG + 1)  // offsets array length
#define NB 98              // ceil(N_TOT / 1024)

typedef __attribute__((ext_vector_type(8))) __bf16 bf16x8;
typedef __attribute__((ext_vector_type(4))) float f32x4;

// ---- d_ws layout (u32 element offsets) -------------------------------------
// [0] flag (idx width probe)   [1] ucnt (number of work units)
#define WS_OFF 64                    // off[N_TOT]: counts -> exclusive offsets
#define WS_RUN (WS_OFF + N_TOT + 1)  // run[N_SEG]: rank-scatter cursors
#define WS_BSUM (WS_RUN + N_SEG)     // bsum[128]
#define WS_BPRE (WS_BSUM + 128)      // bpre[128]
#define WS_UNITS (WS_BPRE + 128)     // uint2 units[300K] (600K u32, 8B aligned)
#define WS_ORDER (WS_UNITS + 600000) // order[1.6M]
// total ~= 2.4M u32 = 9.6 MB

// ---------------------------------------------------------------------------
// Probe: int64 index => every odd 32-bit word is 0. flag=1 => int32 layout.
// ---------------------------------------------------------------------------
__global__ void idx_probe_kernel(const unsigned* __restrict__ idx32,
                                 unsigned* __restrict__ flag, int n) {
  unsigned v = 0;
  const int stride = gridDim.x * blockDim.x;
  for (int i = blockIdx.x * blockDim.x + threadIdx.x; i < n; i += stride)
    v |= idx32[2 * i + 1];
  if (v) atomicOr(flag, 1u);
}

// vectorized histogram: uint4 = 2 int64 elems or 4 int32 elems
__global__ void hist_kernel(const uint4* __restrict__ idx4,
                            const unsigned* __restrict__ flag,
                            unsigned* __restrict__ cnt, int n) {
  const bool idx64 = (*flag == 0u);
  const int stride = gridDim.x * blockDim.x;
  const int t0 = blockIdx.x * blockDim.x + threadIdx.x;
  if (idx64) {
    const int nv = n >> 1;  // uint4 count
    for (int i = t0; i < nv; i += stride) {
      const uint4 v = idx4[i];
      atomicAdd(&cnt[v.x], 1u);
      atomicAdd(&cnt[v.z], 1u);
    }
  } else {
    const int nv = n >> 2;
    for (int i = t0; i < nv; i += stride) {
      const uint4 v = idx4[i];
      atomicAdd(&cnt[v.x], 1u);
      atomicAdd(&cnt[v.y], 1u);
      atomicAdd(&cnt[v.z], 1u);
      atomicAdd(&cnt[v.w], 1u);
    }
  }
}

// ---- coalesced exclusive scan over off[N_TOT], fused unit-build -------------
__global__ __launch_bounds__(1024) void scan_bsum(const unsigned* __restrict__ off,
                                                  unsigned* __restrict__ bsum) {
  __shared__ unsigned ws[16];
  const int t = threadIdx.x;
  const int i = blockIdx.x * 1024 + t;
  unsigned v = (i < N_TOT) ? off[i] : 0u;
#pragma unroll
  for (int d = 1; d < 64; d <<= 1) v += __shfl_xor(v, d);
  if ((t & 63) == 0) ws[t >> 6] = v;
  __syncthreads();
  if (t == 0) {
    unsigned s = 0;
#pragma unroll
    for (int w = 0; w < 16; ++w) s += ws[w];
    bsum[blockIdx.x] = s;
  }
}

__global__ __launch_bounds__(128) void scan_btop(unsigned* __restrict__ bsum,
                                                 unsigned* __restrict__ bpre) {
  __shared__ unsigned part[128];
  const int t = threadIdx.x;
  unsigned v = (t < NB) ? bsum[t] : 0u;
  part[t] = v;
  __syncthreads();
  for (int d = 1; d < 128; d <<= 1) {
    const unsigned u = (t >= d) ? part[t - d] : 0u;
    __syncthreads();
    part[t] += u;
    __syncthreads();
  }
  bpre[t] = part[t] - v;  // exclusive
}

// scan_fixup + unit_build fused: thread for segment s has base=excl, count=v
// locally -> emits the <=16-row units directly (wave-aggregated ucnt atomic),
// zeroes the rare out rows (empty / multi-unit) so no 51 MB out-memset needed.
__global__ __launch_bounds__(1024) void scan_fixup_build(
    unsigned* __restrict__ off, unsigned* __restrict__ run,
    const unsigned* __restrict__ bpre, uint2* __restrict__ units,
    unsigned* __restrict__ ucnt, float* __restrict__ out) {
  __shared__ unsigned wsum[16], wpre[16];
  const int t = threadIdx.x;
  const int lane = t & 63;
  const int wv = t >> 6;
  const int i = blockIdx.x * 1024 + t;
  const unsigned v = (i < N_TOT) ? off[i] : 0u;
  unsigned s = v;
#pragma unroll
  for (int d = 1; d < 64; d <<= 1) {
    const unsigned u = __shfl_up(s, d);
    if (lane >= d) s += u;
  }
  if (lane == 63) wsum[wv] = s;
  __syncthreads();
  if (t < 16) {
    unsigned w = wsum[t];
    unsigned ps = w;
#pragma unroll
    for (int d = 1; d < 16; d <<= 1) {
      const unsigned u = __shfl_up(ps, d, 16);
      if (t >= d) ps += u;
    }
    wpre[t] = ps - w;  // exclusive across waves
  }
  __syncthreads();
  const unsigned excl = (s - v) + wpre[wv] + bpre[blockIdx.x];
  if (i < N_TOT) off[i] = excl;
  if (i < N_SEG) run[i] = excl;

  // ---- fused unit emission ------------------------------------------------
  const unsigned c = (i < N_SEG) ? v : 0u;
  const unsigned nu = (c + 15u) >> 4;
  if (i < N_SEG && (c == 0u || nu > 1u)) {  // rare rows: zero for atomic base
    f32x4* orow = (f32x4*)(out + (size_t)i * DIM);
#pragma unroll
    for (int k = 0; k < DIM / 4; ++k) orow[k] = (f32x4){0.f, 0.f, 0.f, 0.f};
  }
  // wave-aggregated allocation in units[]
  unsigned inc = nu;
#pragma unroll
  for (int d = 1; d < 64; d <<= 1) {
    const unsigned u = __shfl_up(inc, d);
    if (lane >= d) inc += u;
  }
  unsigned base = 0;
  if (lane == 63 && inc > 0) base = atomicAdd(ucnt, inc);
  base = __shfl(base, 63);
  unsigned pos = base + inc - nu;
  const unsigned solo = (nu == 1u) ? (1u << 23) : 0u;
  for (unsigned k = 0; k < nu; ++k) {
    const unsigned cnt = min(16u, c - 16u * k);
    uint2 ent;
    ent.x = excl + 16u * k;
    ent.y = (unsigned)i | ((cnt - 1u) << 17) | solo;
    units[pos + k] = ent;
  }
}

// vectorized rank-scatter: uint4 = 2 int64 elems or 4 int32 elems
__global__ void rank_kernel(const uint4* __restrict__ idx4,
                            const unsigned* __restrict__ flag,
                            unsigned* __restrict__ run,
                            unsigned* __restrict__ order, int n) {
  const bool idx64 = (*flag == 0u);
  const int stride = gridDim.x * blockDim.x;
  const int t0 = blockIdx.x * blockDim.x + threadIdx.x;
  if (idx64) {
    const int nv = n >> 1;
    for (int i = t0; i < nv; i += stride) {
      const uint4 v = idx4[i];
      unsigned p0 = atomicAdd(&run[v.x], 1u);
      order[p0] = 2u * i;
      unsigned p1 = atomicAdd(&run[v.z], 1u);
      order[p1] = 2u * i + 1u;
    }
  } else {
    const int nv = n >> 2;
    for (int i = t0; i < nv; i += stride) {
      const uint4 v = idx4[i];
      unsigned p0 = atomicAdd(&run[v.x], 1u);
      order[p0] = 4u * i;
      unsigned p1 = atomicAdd(&run[v.y], 1u);
      order[p1] = 4u * i + 1u;
      unsigned p2 = atomicAdd(&run[v.z], 1u);
      order[p2] = 4u * i + 2u;
      unsigned p3 = atomicAdd(&run[v.w], 1u);
      order[p3] = 4u * i + 3u;
    }
  }
}

// ---------------------------------------------------------------------------
// Main (EXACT R7 structure, measured ~253 us): one wave per 16-row unit,
// 3-deep rotating prefetch: descriptors 3 ahead, order-ids 2 ahead, e-row
// data 1 ahead. Every vmem wait is >= 1 iteration old. Runs fat at (256,2):
// tighter launch-bounds caps spilled to GBs of scratch HBM (R3/R6);
// unit-pair restructure regressed (R8) -> single-unit iterations.
//
// Fragment layouts (mfma_f32_16x16x32_bf16, m89-verified):
//   A (lane l, elem j): e[row_{l&15}][32t + (l>>4)*8 + j]
//   B (lane l, elem j): W[k0*16 + (l&15)][32t + (l>>4)*8 + j]   (LDS frags)
//   C/D (lane l, reg r): h[tile row (l>>4)*4 + r][k0*16 + (l&15)]
// ---------------------------------------------------------------------------
__global__ __launch_bounds__(256, 2) void fused_main(
    const float* __restrict__ e, const float* __restrict__ W,
    const float* __restrict__ bias_p, const unsigned* __restrict__ order,
    const uint2* __restrict__ units, const unsigned* __restrict__ ucnt,
    float* __restrict__ out) {
  __shared__ bf16x8 wlds[2048];  // 32 KiB: [k0][t][lane] fragment-major

  const int tid = threadIdx.x;
  const int wave = tid >> 6;
  const int lane = tid & 63;
  const int lr = lane & 15;
  const int lg = lane >> 4;

  // one-time: stage W as bf16 fragments into LDS
#pragma unroll
  for (int j = 0; j < 8; ++j) {
    const int g = (tid << 3) | j;
    const int gl = g & 63;
    const int tt = (g >> 6) & 3;
    const int k0 = g >> 8;
    const int row = k0 * 16 + (gl & 15);
    const int col = tt * 32 + (gl >> 4) * 8;
    const float* src = W + (size_t)row * DIM + col;
    f32x4 w0 = *(const f32x4*)src;
    f32x4 w1 = *(const f32x4*)(src + 4);
    bf16x8 f;
    f[0] = (__bf16)w0[0]; f[1] = (__bf16)w0[1];
    f[2] = (__bf16)w0[2]; f[3] = (__bf16)w0[3];
    f[4] = (__bf16)w1[0]; f[5] = (__bf16)w1[1];
    f[6] = (__bf16)w1[2]; f[7] = (__bf16)w1[3];
    wlds[g] = f;
  }
  __syncthreads();

  float bias[8];
#pragma unroll
  for (int k0 = 0; k0 < 8; ++k0) bias[k0] = bias_p[k0 * 16 + lr];

  const int n_units = (int)*ucnt;
  const int wid = blockIdx.x * 4 + wave;
  const int nw = gridDim.x * 4;
  if (wid >= n_units) return;

  // ---- prologue: fill the 3-deep pipeline ---------------------------------
  uint2 eA = units[wid];
  uint2 eB = units[(wid + nw < n_units) ? wid + nw : n_units - 1];
  uint2 eC = units[(wid + 2 * nw < n_units) ? wid + 2 * nw : n_units - 1];

  const int cA0 = (int)((eA.y >> 17) & 15u) + 1;
  unsigned idCur = order[eA.x + (lr < cA0 ? lr : cA0 - 1)];
  f32x4 eload[8];
  {
    const float* erow = e + (size_t)idCur * DIM + lg * 8;
#pragma unroll
    for (int t = 0; t < 4; ++t) {
      eload[2 * t]     = *(const f32x4*)(erow + t * 32);
      eload[2 * t + 1] = *(const f32x4*)(erow + t * 32 + 4);
    }
  }
  const int cB0 = (int)((eB.y >> 17) & 15u) + 1;
  unsigned idNext = order[eB.x + (lr < cB0 ? lr : cB0 - 1)];

  for (int u = wid; u < n_units; u += nw) {
    // decode CURRENT before rotation
    const int seg = (int)(eA.y & 0x1FFFFu);
    const int cnt = (int)((eA.y >> 17) & 15u) + 1;
    const bool solo = (eA.y >> 23) & 1u;

    // 1. convert current e-tile (vmcnt wait: eload issued >=1 iter ago)
    bf16x8 afrag[4];
#pragma unroll
    for (int t = 0; t < 4; ++t) {
      f32x4 a0 = eload[2 * t], a1 = eload[2 * t + 1];
      bf16x8 f;
      f[0] = (__bf16)a0[0]; f[1] = (__bf16)a0[1];
      f[2] = (__bf16)a0[2]; f[3] = (__bf16)a0[3];
      f[4] = (__bf16)a1[0]; f[5] = (__bf16)a1[1];
      f[6] = (__bf16)a1[2]; f[7] = (__bf16)a1[3];
      afrag[t] = f;
    }

    // 2. issue data loads for u+nw (ids loaded last iteration -> no stall)
    {
      const float* erow = e + (size_t)idNext * DIM + lg * 8;
#pragma unroll
      for (int t = 0; t < 4; ++t) {
        eload[2 * t]     = *(const f32x4*)(erow + t * 32);
        eload[2 * t + 1] = *(const f32x4*)(erow + t * 32 + 4);
      }
    }
    // 3. issue ids for u+2nw (descriptor eC loaded last iteration)
    {
      const int cC = (int)((eC.y >> 17) & 15u) + 1;
      idNext = order[eC.x + (lr < cC ? lr : cC - 1)];
    }
    // 4. issue descriptor for u+3nw
    uint2 eC_next =
        units[(u + 3 * nw < n_units) ? u + 3 * nw : n_units - 1];

    // 5. MFMA (LDS operands, lgkmcnt only) — half-split keeps acc at 16 regs
    float colsum[8] = {0.f, 0.f, 0.f, 0.f, 0.f, 0.f, 0.f, 0.f};
#pragma unroll
    for (int half = 0; half < 2; ++half) {
      f32x4 acc[4];
#pragma unroll
      for (int k = 0; k < 4; ++k) acc[k] = (f32x4){0.f, 0.f, 0.f, 0.f};
#pragma unroll
      for (int t = 0; t < 4; ++t) {
#pragma unroll
        for (int k = 0; k < 4; ++k) {
          bf16x8 bf = wlds[((half * 4 + k) * 4 + t) * 64 + lane];
          acc[k] = __builtin_amdgcn_mfma_f32_16x16x32_bf16(afrag[t], bf,
                                                           acc[k], 0, 0, 0);
        }
      }
#pragma unroll
      for (int r = 0; r < 4; ++r) {
        const bool valid = (lg * 4 + r) < cnt;
#pragma unroll
        for (int k = 0; k < 4; ++k) {
          const float v = fmaxf(acc[k][r] + bias[half * 4 + k], 0.f);
          colsum[half * 4 + k] += valid ? v : 0.f;
        }
      }
    }

    // 6. cross-lane reduce; lanes 0..15 hold the 128 column sums
#pragma unroll
    for (int k0 = 0; k0 < 8; ++k0) {
      float s = colsum[k0];
      s += __shfl_xor(s, 16);
      s += __shfl_xor(s, 32);
      colsum[k0] = s;
    }
    if (lg == 0) {
      float* orow = out + (size_t)seg * DIM + lr;
      if (solo) {
#pragma unroll
        for (int k0 = 0; k0 < 8; ++k0) orow[k0 * 16] = colsum[k0];
      } else {
#pragma unroll
        for (int k0 = 0; k0 < 8; ++k0)
          unsafeAtomicAdd(orow + k0 * 16, colsum[k0]);
      }
    }

    // 7. rotate pipeline
    eA = eB;
    eB = eC;
    eC = eC_next;
  }
}

extern "C" void kernel_launch(void* const* d_in, const int* in_sizes, int n_in,
                              void* d_out, int out_size, void* d_ws, size_t ws_size,
                              hipStream_t stream) {
  const float* e = (const float*)d_in[0];
  const int* idx = (const int*)d_in[1];
  const float* W = (const float*)d_in[2];
  const float* b = (const float*)d_in[3];
  float* out = (float*)d_out;
  unsigned* ws32 = (unsigned*)d_ws;

  const int n_e = in_sizes[0] / DIM;  // 1,600,000 rows

  // zero flag + ucnt + off[] only (~400 KB); out rows handled in fixup_build
  hipMemsetAsync(d_ws, 0, (size_t)(WS_OFF + N_TOT) * sizeof(unsigned), stream);

  idx_probe_kernel<<<304, 256, 0, stream>>>((const unsigned*)idx, ws32,
                                            n_e / 2);
  hist_kernel<<<1024, 256, 0, stream>>>((const uint4*)idx, ws32, ws32 + WS_OFF,
                                        n_e);
  scan_bsum<<<NB, 1024, 0, stream>>>(ws32 + WS_OFF, ws32 + WS_BSUM);
  scan_btop<<<1, 128, 0, stream>>>(ws32 + WS_BSUM, ws32 + WS_BPRE);
  scan_fixup_build<<<NB, 1024, 0, stream>>>(
      ws32 + WS_OFF, ws32 + WS_RUN, ws32 + WS_BPRE,
      (uint2*)(ws32 + WS_UNITS), ws32 + 1, out);
  rank_kernel<<<1024, 256, 0, stream>>>((const uint4*)idx, ws32, ws32 + WS_RUN,
                                        ws32 + WS_ORDER, n_e);
  fused_main<<<2048, 256, 0, stream>>>(e, W, b, ws32 + WS_ORDER,
                                       (const uint2*)(ws32 + WS_UNITS),
                                       ws32 + 1, out);
}